// Round 9
// baseline (1710.048 us; speedup 1.0000x reference)
//
#include <hip/hip_runtime.h>
#include <hip/hip_bf16.h>

#define D_DIM 1024
#define NTOK 267735
#define NEXT_ 267737   // + 2 cluster columns
#define HEADN 20000

typedef __attribute__((ext_vector_type(8))) short bf16x8;
typedef __attribute__((ext_vector_type(4))) float f32x4;

__device__ __forceinline__ int seg_of(int c){
  if (c < HEADN)  return 0;
  if (c < 20008)  return 1;
  if (c < 20016)  return 2;
  if (c < 200000) return 3;
  if (c < NTOK)   return 4;
  return 0; // cluster columns belong to head softmax
}

__device__ __forceinline__ unsigned pack2(float x, float y){
  __hip_bfloat16 a = __float2bfloat16(x);
  __hip_bfloat16 b = __float2bfloat16(y);
  unsigned short ua = *reinterpret_cast<unsigned short*>(&a);
  unsigned short ub = *reinterpret_cast<unsigned short*>(&b);
  return (unsigned)ua | ((unsigned)ub << 16);
}

#define BM 128
#define BN 64
#define BK 32
#define NTHREADS 256        // 4 waves: 2 row-slabs x 2 col-slabs, wave tile 64x32
#define KSTEPS (D_DIM/BK)   // 32
#define NROWB 8             // 1024/128 row-blocks per col strip
#define NCOLT 4184          // ceil(NEXT_/64)
#define NBLK (NROWB*NCOLT)  // 33472

#define APRIME_OFF 32768                      // byte offset of A' in ws
#define APRIME_BYTES (1024*1024*2)            // 2 MB bf16 fragment-ordered hidden

// LDS layout for B: [row][32] shorts (64B row). 16B chunk c of row r stored at
// chunk index c ^ ((r>>1)&3): writes conflict-free, b128 frag reads 2-way (free).
// Verified R2/R3/R5/R8: SQ_LDS_BANK_CONFLICT == 0.
__device__ __forceinline__ int swz_w(int r, int k4){   // short offset for 8B write
  int c = (k4 >> 1) ^ ((r >> 1) & 3);
  return r*32 + c*8 + (k4 & 1)*4;
}
__device__ __forceinline__ int swz_r(int row, int q){  // short offset for 16B read
  return row*32 + ((q ^ ((row >> 1) & 3)) << 3);
}

// Convert hidden (1024x1024 f32) -> A' bf16 in MFMA-fragment order:
// A'[rb(64)][kc(128)][r16(16)][e(8)]; element (row,k) at rb=row/16, kc=k/8,
// r16=row%16, e=k%8. A wave's frag load (lane l: q=l>>4, r16=l&15) is then
// 1024 contiguous bytes -> coalesced global b128s, L2-resident (2 MB).
__global__ void prep_convert(const float* __restrict__ hidden,
                             unsigned short* __restrict__ Ap)
{
  int t = blockIdx.x * blockDim.x + threadIdx.x;   // 0..131071
  int r16 = t & 15, kc = (t >> 4) & 127, rb = t >> 11;
  const float4* src = reinterpret_cast<const float4*>(hidden + ((size_t)(rb*16 + r16) * D_DIM + kc*8));
  float4 x = src[0], y = src[1];
  uint4 o;
  o.x = pack2(x.x, x.y); o.y = pack2(x.z, x.w);
  o.z = pack2(y.x, y.y); o.w = pack2(y.z, y.w);
  reinterpret_cast<uint4*>(Ap)[t] = o;             // dst = t*16B: fully coalesced
}

// Per-(row, segment) sum of exp(logit + bias) into accg[row*8 + seg].
// Operating point change vs R8: wave tile 64x32 (acc 32 AGPR) -> ~75 total
// regs -> 6 blocks/CU (24 waves, was 16): lockstep stalls hidden by TLP.
// A direct-from-global in fragment order (R8-proven); B cvt-staged into
// swizzled LDS, double-buffered, issue-early/write-late, ONE barrier/step.
// XCD remap: the 8 row-blocks sharing one 64-col W strip -> same XCD.
__global__ __launch_bounds__(NTHREADS, 6) void gemm_lse_adir(
    const unsigned short* __restrict__ Ap, const float* __restrict__ W,
    const float* __restrict__ bias,   const float* __restrict__ cw,
    const float* __restrict__ cb,     float* __restrict__ accg)
{
  const int b = blockIdx.x;
  const int k8 = b & 7;                // XCD slot
  const int sq_ = b >> 3;              // sequence within XCD
  const int xb = sq_ & 7;              // row-block 0..7 (inner: sharers adjacent)
  const int yb = (sq_ >> 3) * 8 + k8;  // col-strip
  if (yb >= NCOLT) return;

  __shared__ unsigned short lsB0[BN * 32];   // 4 KB
  __shared__ unsigned short lsB1[BN * 32];   // 4 KB

  const int tid = threadIdx.x;
  const int rowBase = xb * BM;
  const int colBase = yb * BN;

  // ---- B staging assignments: 512 float4s of the 64x32 f32 tile, 2/thread ----
  const float* bSrc[2]; int bRow[2], bK4[2];
#pragma unroll
  for (int i=0;i<2;++i){
    int idx = tid + NTHREADS*i;            // 0..511
    bRow[i] = idx >> 3; bK4[i] = idx & 7;
    int c = colBase + bRow[i];
    const float* base;
    if (c < NTOK)       base = W  + (size_t)c * D_DIM;
    else if (c < NEXT_) base = cw + (size_t)(c - NTOK) * D_DIM;
    else                base = W;          // dummy (masked in epilogue)
    bSrc[i] = base + bK4[i]*4;
  }

  const int lane = tid & 63;
  const int wv = tid >> 6;
  const int wm = wv >> 1;   // 0..1 : 64-row slab
  const int wn = wv & 1;    // 0..1 : 32-col slab
  const int q  = lane >> 4; // k-chunk
  const int r16 = lane & 15;

  const int wB0 = swz_w(bRow[0], bK4[0]), wB1 = swz_w(bRow[1], bK4[1]);
  const int rB0 = swz_r(wn*32 +  0 + r16, q), rB1 = swz_r(wn*32 + 16 + r16, q);

  // A' base for this wave: frag i at aBase + i*16384 + kt*512 (ushort units)
  const unsigned short* aBase = Ap + (size_t)(xb*8 + wm*4)*16384 + q*128 + r16*8;

  f32x4 acc[4][2];
#pragma unroll
  for (int i=0;i<4;++i){ acc[i][0] = (f32x4){0,0,0,0}; acc[i][1] = (f32x4){0,0,0,0}; }

  // prologue: B tile 0 -> buf0
  {
    float4 v0 = *reinterpret_cast<const float4*>(bSrc[0]);
    float4 v1 = *reinterpret_cast<const float4*>(bSrc[1]);
    unsigned* p;
    p = reinterpret_cast<unsigned*>(&lsB0[wB0]); p[0] = pack2(v0.x, v0.y); p[1] = pack2(v0.z, v0.w);
    p = reinterpret_cast<unsigned*>(&lsB0[wB1]); p[0] = pack2(v1.x, v1.y); p[1] = pack2(v1.z, v1.w);
  }
  __syncthreads();

  for (int kt = 0; kt < KSTEPS; ++kt){
    unsigned short* Lr = (kt & 1) ? lsB1 : lsB0;   // compute buffer
    unsigned short* Lw = (kt & 1) ? lsB0 : lsB1;   // next-tile buffer
    const bool havenext = (kt + 1 < KSTEPS);

    // issue-early: next B tile (8 regs live across MFMA phase)
    float4 nb0, nb1;
    if (havenext){
      nb0 = *reinterpret_cast<const float4*>(bSrc[0] + (kt+1)*BK);
      nb1 = *reinterpret_cast<const float4*>(bSrc[1] + (kt+1)*BK);
    }

    // B fragments from LDS (2 live)
    bf16x8 bf0 = *reinterpret_cast<const bf16x8*>(&Lr[rB0]);
    bf16x8 bf1 = *reinterpret_cast<const bf16x8*>(&Lr[rB1]);

    // A fragments direct from global, loaded per row-frag (low liveness)
#pragma unroll
    for (int i=0;i<4;++i){
      bf16x8 af = *reinterpret_cast<const bf16x8*>(aBase + i*16384 + kt*512);
      acc[i][0] = __builtin_amdgcn_mfma_f32_16x16x32_bf16(af, bf0, acc[i][0], 0,0,0);
      acc[i][1] = __builtin_amdgcn_mfma_f32_16x16x32_bf16(af, bf1, acc[i][1], 0,0,0);
    }

    // write-late: next B tile into the other buffer (its previous readers
    // finished before the preceding barrier -> one barrier per step is safe)
    if (havenext){
      unsigned* p;
      p = reinterpret_cast<unsigned*>(&Lw[wB0]); p[0] = pack2(nb0.x, nb0.y); p[1] = pack2(nb0.z, nb0.w);
      p = reinterpret_cast<unsigned*>(&Lw[wB1]); p[0] = pack2(nb1.x, nb1.y); p[1] = pack2(nb1.z, nb1.w);
    }
    __syncthreads();
  }

  // ---- fused epilogue: exp + segmented reduce + atomic ----
  int sq[2]; float bq[2];
#pragma unroll
  for (int f=0; f<2; ++f){
    int c = colBase + wn*32 + f*16 + r16;
    if (c < NTOK)       { sq[f] = seg_of(c); bq[f] = bias[c]; }
    else if (c < NEXT_) { sq[f] = 0;         bq[f] = cb[c - NTOK]; }
    else                { sq[f] = -1;        bq[f] = 0.f; }
  }
  int sfirst = seg_of(colBase);
  int clast  = colBase + BN - 1; if (clast > NEXT_-1) clast = NEXT_-1;
  int slast  = seg_of(clast);
  int smin = sfirst, smax = slast;
  if (slast < sfirst){ smin = 0; smax = 4; }   // wrap tile at N_TOKEN boundary

#pragma unroll
  for (int i=0;i<4;++i){
#pragma unroll
    for (int r=0;r<4;++r){
      float e0 = __expf(acc[i][0][r] + bq[0]);
      float e1 = __expf(acc[i][1][r] + bq[1]);
      int rowg = rowBase + wm*64 + i*16 + (lane>>4)*4 + r;   // C/D: row=(l>>4)*4+reg
      for (int s2 = smin; s2 <= smax; ++s2){
        float p = ((sq[0]==s2) ? e0 : 0.f) + ((sq[1]==s2) ? e1 : 0.f);
#pragma unroll
        for (int off=1; off<16; off<<=1) p += __shfl_xor(p, off, 16);
        if ((lane & 15) == 0 && p != 0.f) atomicAdd(&accg[rowg*8 + s2], p);
      }
    }
  }
}

// One wave per row: target logit + routing logit + final nll.
__global__ __launch_bounds__(256) void finalize_kernel(
    const float* __restrict__ hidden, const int* __restrict__ target,
    const float* __restrict__ W,      const float* __restrict__ bias,
    const float* __restrict__ cw,     const float* __restrict__ cb,
    const float* __restrict__ accg,   float* __restrict__ out)
{
  const int row  = blockIdx.x * 4 + (threadIdx.x >> 6);
  const int lane = threadIdx.x & 63;
  const int t = target[row];

  const float4* h4 = reinterpret_cast<const float4*>(hidden + (size_t)row * D_DIM);
  const float4* w1 = reinterpret_cast<const float4*>(W + (size_t)t * D_DIM);
  int s = 0; const float* jraw = W; float jb = 0.f;
  if (t >= HEADN){
    if      (t < 20008)  { s=1; jraw = W;          jb = bias[0]; }  // j = 0
    else if (t < 20016)  { s=2; jraw = W + D_DIM;  jb = bias[1]; }  // j = 1
    else if (t < 200000) { s=3; jraw = cw + D_DIM; jb = cb[1];   }  // j = 20001 -> cluster 1
    else                 { s=4; jraw = cw;         jb = cb[0];   }  // j = 20000 -> cluster 0
  }
  const float4* w2 = reinterpret_cast<const float4*>(jraw);

  float p1 = 0.f, p2 = 0.f;
#pragma unroll
  for (int j=0;j<4;++j){
    float4 hv = h4[lane + 64*j];
    float4 av = w1[lane + 64*j];
    float4 bv = w2[lane + 64*j];
    p1 += hv.x*av.x + hv.y*av.y + hv.z*av.z + hv.w*av.w;
    p2 += hv.x*bv.x + hv.y*bv.y + hv.z*bv.z + hv.w*bv.w;
  }
#pragma unroll
  for (int off=32; off; off>>=1){
    p1 += __shfl_xor(p1, off, 64);
    p2 += __shfl_xor(p2, off, 64);
  }

  if (lane == 0){
    float lseH = __logf(accg[row*8 + 0]);
    float nll;
    if (t < HEADN){
      nll = -(p1 + bias[t] - lseH);
    } else {
      float lseS = __logf(accg[row*8 + s]);
      nll = -((p2 + jb - lseH) + (p1 + bias[t] - lseS));
    }
    out[row] = nll;
  }
}

extern "C" void kernel_launch(void* const* d_in, const int* in_sizes, int n_in,
                              void* d_out, int out_size, void* d_ws, size_t ws_size,
                              hipStream_t stream)
{
  const float* hidden = (const float*)d_in[0];
  const int*   target = (const int*)  d_in[1];
  const float* W      = (const float*)d_in[2];
  const float* bias   = (const float*)d_in[3];
  const float* cw     = (const float*)d_in[4];
  const float* cb     = (const float*)d_in[5];
  float* out  = (float*)d_out;
  float* accg = (float*)d_ws;          // [1024][8] fp32 sum-of-exp accumulators
  unsigned short* Ap = (unsigned short*)((char*)d_ws + APRIME_OFF);

  hipMemsetAsync(accg, 0, 1024*8*sizeof(float), stream);

  prep_convert<<<512, 256, 0, stream>>>(hidden, Ap);
  gemm_lse_adir<<<NBLK, NTHREADS, 0, stream>>>(Ap, W, bias, cw, cb, accg);
  finalize_kernel<<<256, 256, 0, stream>>>(hidden, target, W, bias, cw, cb, accg, out);
}

// Round 10
// 943.121 us; speedup vs baseline: 1.8132x; 1.8132x over previous
//
#include <hip/hip_runtime.h>
#include <hip/hip_bf16.h>

#define D_DIM 1024
#define NTOK 267735
#define NEXT_ 267737   // + 2 cluster columns
#define HEADN 20000

typedef __attribute__((ext_vector_type(8))) short bf16x8;
typedef __attribute__((ext_vector_type(4))) float f32x4;

__device__ __forceinline__ int seg_of(int c){
  if (c < HEADN)  return 0;
  if (c < 20008)  return 1;
  if (c < 20016)  return 2;
  if (c < 200000) return 3;
  if (c < NTOK)   return 4;
  return 0; // cluster columns belong to head softmax
}

__device__ __forceinline__ unsigned pack2(float x, float y){
  __hip_bfloat16 a = __float2bfloat16(x);
  __hip_bfloat16 b = __float2bfloat16(y);
  unsigned short ua = *reinterpret_cast<unsigned short*>(&a);
  unsigned short ub = *reinterpret_cast<unsigned short*>(&b);
  return (unsigned)ua | ((unsigned)ub << 16);
}

#define BM 512
#define BN 128
#define BK 32
#define NTHREADS 1024       // 16 waves: 8 row-slabs x 2 col-slabs, wave tile 64x64
#define KSTEPS (D_DIM/BK)   // 32
#define NROWB 2             // 1024/512
#define NCOLT 2092          // ceil(NEXT_/128)
#define NBLK 4192           // 8 XCD * 524 (8 dead pad blocks)

#define APRIME_OFF 32768                      // byte offset of A' in ws
#define APRIME_BYTES (1024*1024*2)            // 2 MB bf16 fragment-ordered hidden

// LDS layout for B: [row][32] shorts (64B row). 16B chunk c of row r stored at
// chunk index c ^ ((r>>1)&3): writes conflict-free, b128 frag reads 2-way (free).
// Verified R2/R3/R5/R8: SQ_LDS_BANK_CONFLICT == 0.
__device__ __forceinline__ int swz_w(int r, int k4){   // short offset for 8B write
  int c = (k4 >> 1) ^ ((r >> 1) & 3);
  return r*32 + c*8 + (k4 & 1)*4;
}
__device__ __forceinline__ int swz_r(int row, int q){  // short offset for 16B read
  return row*32 + ((q ^ ((row >> 1) & 3)) << 3);
}

// Convert hidden (1024x1024 f32) -> A' bf16 in MFMA-fragment order:
// A'[rb(64)][kc(128)][r16(16)][e(8)]; element (row,k) at rb=row/16, kc=k/8,
// r16=row%16, e=k%8. A wave's frag load (lane l: q=l>>4, r16=l&15) is then
// 1024 contiguous bytes -> coalesced global b128s, L2-resident (2 MB).
__global__ void prep_convert(const float* __restrict__ hidden,
                             unsigned short* __restrict__ Ap)
{
  int t = blockIdx.x * blockDim.x + threadIdx.x;   // 0..131071
  int r16 = t & 15, kc = (t >> 4) & 127, rb = t >> 11;
  const float4* src = reinterpret_cast<const float4*>(hidden + ((size_t)(rb*16 + r16) * D_DIM + kc*8));
  float4 x = src[0], y = src[1];
  uint4 o;
  o.x = pack2(x.x, x.y); o.y = pack2(x.z, x.w);
  o.z = pack2(y.x, y.y); o.w = pack2(y.z, y.w);
  reinterpret_cast<uint4*>(Ap)[t] = o;             // dst = t*16B: fully coalesced
}

// Per-(row, segment) sum of exp(logit + bias) into accg[row*8 + seg].
// R10 change vs R8: BM 256 -> 512 (1024-thread block, 16 waves of the SAME
// 64x64 wave tile) -> block count and barrier-step count HALVE (R9 lesson
// inverted: fewer, bigger steps). Same reg class (~60 arch + 64 acc), same
// 16 waves/CU, B staging = exactly 1 float4/thread. A direct-from-global in
// fragment order (R8-proven); B cvt-staged to swizzled LDS, dbuf,
// issue-early/write-late, ONE barrier/step. XCD remap: the 2 row-blocks
// sharing one 128-col W strip -> same XCD.
__global__ __launch_bounds__(NTHREADS, 1) void gemm_lse_adir(
    const unsigned short* __restrict__ Ap, const float* __restrict__ W,
    const float* __restrict__ bias,   const float* __restrict__ cw,
    const float* __restrict__ cb,     float* __restrict__ accg)
{
  const int b = blockIdx.x;
  const int k8 = b & 7;                // XCD slot
  const int sq_ = b >> 3;              // sequence within XCD (0..523)
  const int xb = sq_ & 1;              // row-block 0..1 (inner: sharers adjacent)
  const int yb = (sq_ >> 1) * 8 + k8;  // col-strip
  if (yb >= NCOLT) return;             // 8 pad blocks

  __shared__ unsigned short lsB0[BN * 32];   // 8 KB
  __shared__ unsigned short lsB1[BN * 32];   // 8 KB

  const int tid = threadIdx.x;
  const int rowBase = xb * BM;
  const int colBase = yb * BN;

  // ---- B staging: 1024 float4s of the 128x32 f32 tile, exactly 1/thread ----
  const float* bSrc; int bRow, bK4;
  {
    bRow = tid >> 3; bK4 = tid & 7;
    int c = colBase + bRow;
    const float* base;
    if (c < NTOK)       base = W  + (size_t)c * D_DIM;
    else if (c < NEXT_) base = cw + (size_t)(c - NTOK) * D_DIM;
    else                base = W;          // dummy (masked in epilogue)
    bSrc = base + bK4*4;
  }

  const int lane = tid & 63;
  const int wv = tid >> 6;   // 0..15
  const int wm = wv >> 1;    // 0..7 : 64-row slab
  const int wn = wv & 1;     // 0..1 : 64-col slab
  const int q  = lane >> 4;  // k-chunk
  const int r16 = lane & 15;

  const int wB0 = swz_w(bRow, bK4);
  const int rB0 = swz_r(wn*64 +  0 + r16, q), rB1 = swz_r(wn*64 + 16 + r16, q);
  const int rB2 = swz_r(wn*64 + 32 + r16, q), rB3 = swz_r(wn*64 + 48 + r16, q);

  // A' fragment pointers: frag i covers rows rowBase + wm*64 + i*16
  // ushort idx = (xb*32 + wm*4 + i)*16384 + (kt*4+q)*128 + r16*8
  const unsigned short* a0 = Ap + (size_t)(xb*32 + wm*4 + 0)*16384 + q*128 + r16*8;
  const unsigned short* a1 = Ap + (size_t)(xb*32 + wm*4 + 1)*16384 + q*128 + r16*8;
  const unsigned short* a2 = Ap + (size_t)(xb*32 + wm*4 + 2)*16384 + q*128 + r16*8;
  const unsigned short* a3 = Ap + (size_t)(xb*32 + wm*4 + 3)*16384 + q*128 + r16*8;

  f32x4 acc[4][4];
#pragma unroll
  for (int i=0;i<4;++i)
#pragma unroll
    for (int j=0;j<4;++j) acc[i][j] = (f32x4){0.f,0.f,0.f,0.f};

  // prologue: B tile 0 -> buf0
  {
    float4 v0 = *reinterpret_cast<const float4*>(bSrc);
    unsigned* p = reinterpret_cast<unsigned*>(&lsB0[wB0]);
    p[0] = pack2(v0.x, v0.y); p[1] = pack2(v0.z, v0.w);
  }
  __syncthreads();

  for (int kt = 0; kt < KSTEPS; ++kt){
    unsigned short* Lr = (kt & 1) ? lsB1 : lsB0;   // compute buffer
    unsigned short* Lw = (kt & 1) ? lsB0 : lsB1;   // next-tile buffer
    const bool havenext = (kt + 1 < KSTEPS);

    // issue-early: next B tile (4 regs live across MFMA phase)
    float4 nb0;
    if (havenext) nb0 = *reinterpret_cast<const float4*>(bSrc + (kt+1)*BK);

    // A fragments direct from global (coalesced 1024B/wave each, L2-resident)
    bf16x8 af0 = *reinterpret_cast<const bf16x8*>(a0 + kt*512);
    bf16x8 af1 = *reinterpret_cast<const bf16x8*>(a1 + kt*512);
    bf16x8 af2 = *reinterpret_cast<const bf16x8*>(a2 + kt*512);
    bf16x8 af3 = *reinterpret_cast<const bf16x8*>(a3 + kt*512);

    // B fragments from LDS
    bf16x8 bf0 = *reinterpret_cast<const bf16x8*>(&Lr[rB0]);
    bf16x8 bf1 = *reinterpret_cast<const bf16x8*>(&Lr[rB1]);
    bf16x8 bf2 = *reinterpret_cast<const bf16x8*>(&Lr[rB2]);
    bf16x8 bf3 = *reinterpret_cast<const bf16x8*>(&Lr[rB3]);

    acc[0][0] = __builtin_amdgcn_mfma_f32_16x16x32_bf16(af0, bf0, acc[0][0], 0,0,0);
    acc[0][1] = __builtin_amdgcn_mfma_f32_16x16x32_bf16(af0, bf1, acc[0][1], 0,0,0);
    acc[0][2] = __builtin_amdgcn_mfma_f32_16x16x32_bf16(af0, bf2, acc[0][2], 0,0,0);
    acc[0][3] = __builtin_amdgcn_mfma_f32_16x16x32_bf16(af0, bf3, acc[0][3], 0,0,0);
    acc[1][0] = __builtin_amdgcn_mfma_f32_16x16x32_bf16(af1, bf0, acc[1][0], 0,0,0);
    acc[1][1] = __builtin_amdgcn_mfma_f32_16x16x32_bf16(af1, bf1, acc[1][1], 0,0,0);
    acc[1][2] = __builtin_amdgcn_mfma_f32_16x16x32_bf16(af1, bf2, acc[1][2], 0,0,0);
    acc[1][3] = __builtin_amdgcn_mfma_f32_16x16x32_bf16(af1, bf3, acc[1][3], 0,0,0);
    acc[2][0] = __builtin_amdgcn_mfma_f32_16x16x32_bf16(af2, bf0, acc[2][0], 0,0,0);
    acc[2][1] = __builtin_amdgcn_mfma_f32_16x16x32_bf16(af2, bf1, acc[2][1], 0,0,0);
    acc[2][2] = __builtin_amdgcn_mfma_f32_16x16x32_bf16(af2, bf2, acc[2][2], 0,0,0);
    acc[2][3] = __builtin_amdgcn_mfma_f32_16x16x32_bf16(af2, bf3, acc[2][3], 0,0,0);
    acc[3][0] = __builtin_amdgcn_mfma_f32_16x16x32_bf16(af3, bf0, acc[3][0], 0,0,0);
    acc[3][1] = __builtin_amdgcn_mfma_f32_16x16x32_bf16(af3, bf1, acc[3][1], 0,0,0);
    acc[3][2] = __builtin_amdgcn_mfma_f32_16x16x32_bf16(af3, bf2, acc[3][2], 0,0,0);
    acc[3][3] = __builtin_amdgcn_mfma_f32_16x16x32_bf16(af3, bf3, acc[3][3], 0,0,0);

    // write-late: next B tile into the other buffer (previous readers of Lw
    // finished before the preceding barrier -> one barrier per step is safe)
    if (havenext){
      unsigned* p = reinterpret_cast<unsigned*>(&Lw[wB0]);
      p[0] = pack2(nb0.x, nb0.y); p[1] = pack2(nb0.z, nb0.w);
    }
    __syncthreads();
  }

  // ---- fused epilogue: exp + segmented reduce + atomic ----
  int sq[4]; float bq[4];
#pragma unroll
  for (int f=0; f<4; ++f){
    int c = colBase + wn*64 + f*16 + r16;
    if (c < NTOK)       { sq[f] = seg_of(c); bq[f] = bias[c]; }
    else if (c < NEXT_) { sq[f] = 0;         bq[f] = cb[c - NTOK]; }
    else                { sq[f] = -1;        bq[f] = 0.f; }
  }
  int sfirst = seg_of(colBase);
  int clast  = colBase + BN - 1; if (clast > NEXT_-1) clast = NEXT_-1;
  int slast  = seg_of(clast);
  int smin = sfirst, smax = slast;
  if (slast < sfirst){ smin = 0; smax = 4; }   // wrap tile at N_TOKEN boundary

#pragma unroll
  for (int i=0;i<4;++i){
#pragma unroll
    for (int r=0;r<4;++r){
      float e[4];
#pragma unroll
      for (int f=0;f<4;++f) e[f] = __expf(acc[i][f][r] + bq[f]);
      int rowg = rowBase + wm*64 + i*16 + (lane>>4)*4 + r;   // C/D: row=(l>>4)*4+reg
      for (int s2 = smin; s2 <= smax; ++s2){
        float p = 0.f;
#pragma unroll
        for (int f=0;f<4;++f) p += (sq[f]==s2) ? e[f] : 0.f;
#pragma unroll
        for (int off=1; off<16; off<<=1) p += __shfl_xor(p, off, 16);
        if ((lane & 15) == 0 && p != 0.f) atomicAdd(&accg[rowg*8 + s2], p);
      }
    }
  }
}

// One wave per row: target logit + routing logit + final nll.
__global__ __launch_bounds__(256) void finalize_kernel(
    const float* __restrict__ hidden, const int* __restrict__ target,
    const float* __restrict__ W,      const float* __restrict__ bias,
    const float* __restrict__ cw,     const float* __restrict__ cb,
    const float* __restrict__ accg,   float* __restrict__ out)
{
  const int row  = blockIdx.x * 4 + (threadIdx.x >> 6);
  const int lane = threadIdx.x & 63;
  const int t = target[row];

  const float4* h4 = reinterpret_cast<const float4*>(hidden + (size_t)row * D_DIM);
  const float4* w1 = reinterpret_cast<const float4*>(W + (size_t)t * D_DIM);
  int s = 0; const float* jraw = W; float jb = 0.f;
  if (t >= HEADN){
    if      (t < 20008)  { s=1; jraw = W;          jb = bias[0]; }  // j = 0
    else if (t < 20016)  { s=2; jraw = W + D_DIM;  jb = bias[1]; }  // j = 1
    else if (t < 200000) { s=3; jraw = cw + D_DIM; jb = cb[1];   }  // j = 20001 -> cluster 1
    else                 { s=4; jraw = cw;         jb = cb[0];   }  // j = 20000 -> cluster 0
  }
  const float4* w2 = reinterpret_cast<const float4*>(jraw);

  float p1 = 0.f, p2 = 0.f;
#pragma unroll
  for (int j=0;j<4;++j){
    float4 hv = h4[lane + 64*j];
    float4 av = w1[lane + 64*j];
    float4 bv = w2[lane + 64*j];
    p1 += hv.x*av.x + hv.y*av.y + hv.z*av.z + hv.w*av.w;
    p2 += hv.x*bv.x + hv.y*bv.y + hv.z*bv.z + hv.w*bv.w;
  }
#pragma unroll
  for (int off=32; off; off>>=1){
    p1 += __shfl_xor(p1, off, 64);
    p2 += __shfl_xor(p2, off, 64);
  }

  if (lane == 0){
    float lseH = __logf(accg[row*8 + 0]);
    float nll;
    if (t < HEADN){
      nll = -(p1 + bias[t] - lseH);
    } else {
      float lseS = __logf(accg[row*8 + s]);
      nll = -((p2 + jb - lseH) + (p1 + bias[t] - lseS));
    }
    out[row] = nll;
  }
}

extern "C" void kernel_launch(void* const* d_in, const int* in_sizes, int n_in,
                              void* d_out, int out_size, void* d_ws, size_t ws_size,
                              hipStream_t stream)
{
  const float* hidden = (const float*)d_in[0];
  const int*   target = (const int*)  d_in[1];
  const float* W      = (const float*)d_in[2];
  const float* bias   = (const float*)d_in[3];
  const float* cw     = (const float*)d_in[4];
  const float* cb     = (const float*)d_in[5];
  float* out  = (float*)d_out;
  float* accg = (float*)d_ws;          // [1024][8] fp32 sum-of-exp accumulators
  unsigned short* Ap = (unsigned short*)((char*)d_ws + APRIME_OFF);

  hipMemsetAsync(accg, 0, 1024*8*sizeof(float), stream);

  prep_convert<<<512, 256, 0, stream>>>(hidden, Ap);
  gemm_lse_adir<<<NBLK, NTHREADS, 0, stream>>>(Ap, W, bias, cw, cb, accg);
  finalize_kernel<<<256, 256, 0, stream>>>(hidden, target, W, bias, cw, cb, accg, out);
}